// Round 8
// baseline (249.764 us; speedup 1.0000x reference)
//
#include <hip/hip_runtime.h>
#include <math.h>

// out[tok, d] = cos(dot(x[tok,:], W1) + b1) * cos(phi) * W2[d] + b2[d]
// D = 1024, tokens = B*S = 32768 (fixed by reference shape).
//
// Round 8: remove the cross-lane reduction from the x-streaming kernel.
// Evidence (r0-r7): every structure that put a shuffle-reduce + cos + store
// on the load-consume path flatlined at 2.4-3.7 TB/s read (r7 counters:
// 2.4 TB/s, VALUBusy 4.8%, occupancy 16.5%) -- waves hold zero memory in
// flight during the ~200+cy reduce tail. The fill kernel saturates (6.7 TB/s)
// at 9% occupancy because its stores are fire-and-forget.
//
//   phase 1 ffq_partial: copy-structured. thread=(row,lane): 4x f4 loads
//            (64B of x), 4 independent vector fmas, ONE float store.
//            No shuffle/LDS/barrier/cos. 134 MB read + 8 MB write.
//   phase 2 ffq_reduce:  64 partials/token -> q. 8 MB (cache-hot), ~4us.
//   phase 3 ffq_out:     rank-1 expand, fill-structured (r5, proven). 131 MB.
//
// Workspace: part[32768*64] floats (8 MiB) at ws+0, q[32768] at ws+2097152.

#define EMBED_D 1024
#define ROW_F4  (EMBED_D / 4)          // 256 f4 per row
#define NTOK    (8 * 4096)
#define P1_BLOCKS 2048
#define P1_PASSES 4                    // 2048 blk * 4 waves = 8192 rows/pass
#define TPB3    16                     // token rows per block, phase 3

typedef float f4 __attribute__((ext_vector_type(4)));

// ---------------- phase 1: per-lane partial dot ----------------
// part[row*64 + lane] = sum_{c} x[row, c*64+lane (f4)] . W1[c*64+lane (f4)]
__global__ __launch_bounds__(256) void ffq_partial(
    const float* __restrict__ x,
    const float* __restrict__ W1,
    float* __restrict__ part)
{
    const int lane = threadIdx.x & 63;
    const int wid  = blockIdx.x * 4 + (threadIdx.x >> 6);   // 0..8191

    const f4* w14 = (const f4*)W1;
    f4 w1r[4];
    #pragma unroll
    for (int c = 0; c < 4; ++c) w1r[c] = w14[c * 64 + lane];

    #pragma unroll
    for (int p = 0; p < P1_PASSES; ++p) {
        const int row = p * 8192 + wid;
        const f4* xr = (const f4*)x + (size_t)row * ROW_F4;
        // 4 independent coalesced loads (1 KB/wave each), 4 indep fma chains
        f4 x0 = xr[0 * 64 + lane];
        f4 x1 = xr[1 * 64 + lane];
        f4 x2 = xr[2 * 64 + lane];
        f4 x3 = xr[3 * 64 + lane];
        f4 a = x0 * w1r[0];
        a += x1 * w1r[1];
        a += x2 * w1r[2];
        a += x3 * w1r[3];
        // one 4B store per 64B read; wave store = 256B contiguous
        part[(size_t)row * 64 + lane] = a.x + a.y + a.z + a.w;
    }
}

// ---------------- phase 2: reduce partials -> q ----------------
// f4 #g covers token g>>4, parts (g%16)*4 .. +3. Width-16 shuffle tree.
__global__ __launch_bounds__(256) void ffq_reduce(
    const float* __restrict__ part,
    const float* __restrict__ b1,
    const float* __restrict__ phi,
    float* __restrict__ q)
{
    const int t = threadIdx.x;
    const int g = blockIdx.x * 256 + t;          // f4 index, 0..524287
    const f4 v = ((const f4*)part)[g];
    float s = (v.x + v.y) + (v.z + v.w);
    s += __shfl_xor(s, 1, 16);
    s += __shfl_xor(s, 2, 16);
    s += __shfl_xor(s, 4, 16);
    s += __shfl_xor(s, 8, 16);
    if ((t & 15) == 0)
        q[g >> 4] = cosf(s + b1[0]) * cosf(phi[0]);
}

// ---------------- phase 3: out[tok,:] = q[tok]*W2 + b2 ----------------
// Fill-kernel structure (r5, verified): thread t owns f4-slot t of a row;
// block writes 16 contiguous rows; q via 4 wave-uniform f4 loads; plain stores.
__global__ __launch_bounds__(256) void ffq_out(
    const float* __restrict__ q_ws,
    const float* __restrict__ W2,
    const float* __restrict__ b2,
    float* __restrict__ out)
{
    const int t = threadIdx.x;                   // f4 slot in row, 0..255

    const f4 w2v = ((const f4*)W2)[t];
    const f4 b2v = ((const f4*)b2)[t];

    const f4* qb = (const f4*)q_ws + blockIdx.x * (TPB3 / 4);
    f4 q0 = qb[0], q1 = qb[1], q2 = qb[2], q3 = qb[3];
    const float qq[TPB3] = { q0.x,q0.y,q0.z,q0.w, q1.x,q1.y,q1.z,q1.w,
                             q2.x,q2.y,q2.z,q2.w, q3.x,q3.y,q3.z,q3.w };

    f4* ob = (f4*)out + (size_t)blockIdx.x * TPB3 * ROW_F4 + t;
    #pragma unroll
    for (int tt = 0; tt < TPB3; ++tt) {
        f4 o;
        o.x = fmaf(qq[tt], w2v.x, b2v.x);
        o.y = fmaf(qq[tt], w2v.y, b2v.y);
        o.z = fmaf(qq[tt], w2v.z, b2v.z);
        o.w = fmaf(qq[tt], w2v.w, b2v.w);
        ob[tt * ROW_F4] = o;                     // 16 independent 16B stores
    }
}

extern "C" void kernel_launch(void* const* d_in, const int* in_sizes, int n_in,
                              void* d_out, int out_size, void* d_ws, size_t ws_size,
                              hipStream_t stream) {
    const float* x   = (const float*)d_in[0];
    const float* W1  = (const float*)d_in[1];
    const float* b1  = (const float*)d_in[2];
    const float* phi = (const float*)d_in[3];
    const float* W2  = (const float*)d_in[4];
    const float* b2  = (const float*)d_in[5];
    float* out = (float*)d_out;

    float* part = (float*)d_ws;                       // 32768*64 = 8 MiB
    float* q    = (float*)d_ws + (size_t)NTOK * 64;   // 32768 floats

    ffq_partial<<<P1_BLOCKS, 256, 0, stream>>>(x, W1, part);
    ffq_reduce <<<NTOK * 16 / 256, 256, 0, stream>>>(part, b1, phi, q);
    ffq_out    <<<NTOK / TPB3, 256, 0, stream>>>(q, W2, b2, out);
}